// Round 9
// baseline (318.575 us; speedup 1.0000x reference)
//
#include <hip/hip_runtime.h>

// ---------------------------------------------------------------------------
// MultiHeadAttention: B=4, S=2048, D=1024, H=16, dk=64
// R9: QKV GEMM with DIRECT global->register A-fragment loads (fp32, 64B
//     segments, XCD-local L2 reuse) + in-register cvt_pkrtz; B double-
//     buffered in LDS via global_load_lds -> ONE barrier per K-step and only
//     48 KB/block-step of LDS traffic (was 144 KB with fp32-A-in-LDS, the
//     R8 bottleneck). No cast kernels. Out-proj/attn unchanged from R8.
// ---------------------------------------------------------------------------

typedef _Float16 fp16;
typedef fp16  fp16x8 __attribute__((ext_vector_type(8)));
typedef fp16  fp16x4 __attribute__((ext_vector_type(4)));
typedef __fp16 h16x2 __attribute__((ext_vector_type(2)));
typedef float f32x4  __attribute__((ext_vector_type(4)));

#define NROWS 8192     // B*S
#define DM    1024
#define SEQ   2048
#define DK    64
#define LOG2E 1.44269504088896340736f
#define QSCALE (0.125f * LOG2E)

__device__ __forceinline__ f32x4 mfma16x16(fp16x8 a, fp16x8 b, f32x4 c) {
    return __builtin_amdgcn_mfma_f32_16x16x32_f16(a, b, c, 0, 0, 0);
}

__device__ __forceinline__ void gload16(const void* g, void* l) {
    __builtin_amdgcn_global_load_lds(
        (const __attribute__((address_space(1))) void*)g,
        (__attribute__((address_space(3))) void*)l, 16, 0, 0);
}

__device__ __forceinline__ fp16x8 cvt8(f32x4 a, f32x4 b) {
    h16x2 r0 = __builtin_amdgcn_cvt_pkrtz(a[0], a[1]);
    h16x2 r1 = __builtin_amdgcn_cvt_pkrtz(a[2], a[3]);
    h16x2 r2 = __builtin_amdgcn_cvt_pkrtz(b[0], b[1]);
    h16x2 r3 = __builtin_amdgcn_cvt_pkrtz(b[2], b[3]);
    fp16x8 v;
    v[0] = (fp16)r0[0]; v[1] = (fp16)r0[1]; v[2] = (fp16)r1[0]; v[3] = (fp16)r1[1];
    v[4] = (fp16)r2[0]; v[5] = (fp16)r2[1]; v[6] = (fp16)r3[0]; v[7] = (fp16)r3[1];
    return v;
}

// ---- transpose 1024x1024 fp32 W[k][n] -> fp16 T[n][k], z-batched x4 ------
__global__ __launch_bounds__(256) void transpose_w_kernel(
    const float* __restrict__ w0, const float* __restrict__ w1,
    const float* __restrict__ w2, const float* __restrict__ w3,
    fp16* __restrict__ t0, fp16* __restrict__ t1,
    fp16* __restrict__ t2, fp16* __restrict__ t3) {
    const int z = blockIdx.z;
    const float* W = (z == 0) ? w0 : (z == 1) ? w1 : (z == 2) ? w2 : w3;
    fp16*       T = (z == 0) ? t0 : (z == 1) ? t1 : (z == 2) ? t2 : t3;
    __shared__ float tile[32][33];
    const int tx = threadIdx.x, ty = threadIdx.y;
    const int bx = blockIdx.x * 32, by = blockIdx.y * 32;
#pragma unroll
    for (int j = 0; j < 4; ++j)
        tile[ty + 8 * j][tx] = W[(size_t)(by + ty + 8 * j) * DM + bx + tx];
    __syncthreads();
#pragma unroll
    for (int j = 0; j < 4; ++j)
        T[(size_t)(bx + ty + 8 * j) * DM + by + tx] = (fp16)tile[tx][ty + 8 * j];
}

// ---- QKV projection GEMM: A fp32 direct-from-global (cast fused in regs),
//      B fp16 via global_load_lds double-buffer; ONE barrier per K-step.
// Grid: 1536 1D. Decode: XCD x = i&7 owns m-slabs [x*8, x*8+8) for all n,z.
__global__ __launch_bounds__(256) void gemm_qkv_kernel(
    const float* __restrict__ Xq, const float* __restrict__ Xk,
    const float* __restrict__ Xv,
    const fp16* __restrict__ Wq, const fp16* __restrict__ Wk,
    const fp16* __restrict__ Wv,
    const float* __restrict__ bq, const float* __restrict__ bk,
    const float* __restrict__ bv,
    fp16* __restrict__ Qb, fp16* __restrict__ Kb, fp16* __restrict__ Vtg) {
    const int i = blockIdx.x;
    const int xcd = i & 7, r = i >> 3;           // r in [0,192)
    const int z = r >> 6, rr = r & 63;
    const int m0 = (xcd * 8 + (rr >> 3)) * 128;  // m-slab, XCD-local
    const int n0 = (rr & 7) * 128;

    const float* __restrict__ A = (z == 0) ? Xq : (z == 1) ? Xk : Xv;
    const fp16* __restrict__ B = (z == 0) ? Wq : (z == 1) ? Wk : Wv;
    const float* __restrict__ bias = (z == 0) ? bq : (z == 1) ? bk : bv;
    fp16* __restrict__ outp = (z == 0) ? Qb : (z == 1) ? Kb : Vtg;
    const float oscale = (z == 0) ? QSCALE : 1.0f;

    const int tid = threadIdx.x;
    const int lane = tid & 63;
    const int w = tid >> 6;
    const int wr = w >> 1, wc = w & 1;
    const int li = lane & 15, lg = lane >> 4;
    const int lrow8 = lane >> 3;
    const int lch8  = (lane & 7) ^ lrow8;        // pre-swizzled B source chunk

    __shared__ fp16 Bt[2][128 * 64];             // 32 KB double buffer

    f32x4 acc[4][4] = {};
    f32x4 areg[4][2][2];                         // fp32 A prefetch (64 VGPR)

    // A fragment base addresses: row = m0 + wr*64 + mf*16 + li; col lg*8
    const float* Abase = &A[(size_t)(m0 + wr * 64 + li) * DM + lg * 8];

    // prologue: stage B(k0=0) into buf0, issue A(k0=0) loads
#pragma unroll
    for (int it = 0; it < 4; ++it) {
        int R = (w * 4 + it) * 8 + lrow8;
        gload16(&B[(size_t)(n0 + R) * DM + lch8 * 8], &Bt[0][(w * 4 + it) * 512]);
    }
#pragma unroll
    for (int mf = 0; mf < 4; ++mf)
#pragma unroll
        for (int ks = 0; ks < 2; ++ks) {
            areg[mf][ks][0] = *(const f32x4*)&Abase[(size_t)mf * 16 * DM + ks * 32];
            areg[mf][ks][1] = *(const f32x4*)&Abase[(size_t)mf * 16 * DM + ks * 32 + 4];
        }

    for (int k0 = 0; k0 < DM; k0 += 64) {
        const int cur = (k0 >> 6) & 1;
        __syncthreads();                         // drains B-stage AND A loads
        if (k0 + 64 < DM) {                      // stage next B tile (async)
#pragma unroll
            for (int it = 0; it < 4; ++it) {
                int R = (w * 4 + it) * 8 + lrow8;
                gload16(&B[(size_t)(n0 + R) * DM + k0 + 64 + lch8 * 8],
                        &Bt[cur ^ 1][(w * 4 + it) * 512]);
            }
        }
        // convert A prefetch (already resident -- barrier drained vmcnt)
        fp16x8 af[4][2];
#pragma unroll
        for (int mf = 0; mf < 4; ++mf)
#pragma unroll
            for (int ks = 0; ks < 2; ++ks)
                af[mf][ks] = cvt8(areg[mf][ks][0], areg[mf][ks][1]);
        // issue next A loads (whole MFMA phase + next barrier to land)
        if (k0 + 64 < DM) {
#pragma unroll
            for (int mf = 0; mf < 4; ++mf)
#pragma unroll
                for (int ks = 0; ks < 2; ++ks) {
                    areg[mf][ks][0] = *(const f32x4*)&Abase[(size_t)mf * 16 * DM + k0 + 64 + ks * 32];
                    areg[mf][ks][1] = *(const f32x4*)&Abase[(size_t)mf * 16 * DM + k0 + 64 + ks * 32 + 4];
                }
        }
        fp16x8 bfr[4][2];
#pragma unroll
        for (int nf = 0; nf < 4; ++nf)
#pragma unroll
            for (int ks = 0; ks < 2; ++ks)
                bfr[nf][ks] = *(const fp16x8*)&Bt[cur][(wc * 64 + nf * 16 + li) * 64 +
                                                       (((ks * 4 + lg) ^ (li & 7)) * 8)];
        __builtin_amdgcn_s_setprio(1);
#pragma unroll
        for (int ks = 0; ks < 2; ++ks)
#pragma unroll
            for (int mf = 0; mf < 4; ++mf)
#pragma unroll
                for (int nf = 0; nf < 4; ++nf)
                    acc[mf][nf] = mfma16x16(af[mf][ks], bfr[nf][ks], acc[mf][nf]);
        __builtin_amdgcn_s_setprio(0);
    }
#pragma unroll
    for (int nf = 0; nf < 4; ++nf) {
        int col = n0 + wc * 64 + nf * 16 + li;
        float bv_ = bias[col];
        if (z == 2) {           // V^T layout [b*1024 + col][s]
#pragma unroll
            for (int mf = 0; mf < 4; ++mf) {
                int rowb = m0 + wr * 64 + mf * 16 + lg * 4;
                fp16x4 pk;
#pragma unroll
                for (int r2 = 0; r2 < 4; ++r2)
                    pk[r2] = (fp16)(acc[mf][nf][r2] + bv_);
                size_t o = ((size_t)(rowb >> 11) * 1024 + col) * SEQ + (rowb & 2047);
                *(fp16x4*)&outp[o] = pk;
            }
        } else {
#pragma unroll
            for (int mf = 0; mf < 4; ++mf)
#pragma unroll
                for (int r2 = 0; r2 < 4; ++r2) {
                    int row = m0 + wr * 64 + mf * 16 + lg * 4 + r2;
                    outp[(size_t)row * DM + col] = (fp16)((acc[mf][nf][r2] + bv_) * oscale);
                }
        }
    }
}

// ---- Out-projection GEMM: fp16 A/B, 128x64 tile, XCD-aware decode --------
__global__ __launch_bounds__(256) void gemm_out_kernel(
    const fp16* __restrict__ A, const fp16* __restrict__ B,
    const float* __restrict__ bias, float* __restrict__ outp) {
    const int i = blockIdx.x;
    const int xcd = i & 7, r = i >> 3;           // r in [0,128)
    const int m0 = (xcd * 8 + (r >> 4)) * 128;
    const int n0 = (r & 15) * 64;

    const int tid = threadIdx.x;
    const int lane = tid & 63;
    const int w = tid >> 6;
    const int wr = w >> 1, wc = w & 1;
    const int li = lane & 15, lg = lane >> 4;
    const int lrow = lane >> 3;
    const int lch  = (lane & 7) ^ lrow;

    __shared__ fp16 At[128 * 64];
    __shared__ fp16 Bt[64 * 64];

    f32x4 acc[4][2] = {};

    for (int k0 = 0; k0 < DM; k0 += 64) {
        __syncthreads();
#pragma unroll
        for (int it = 0; it < 4; ++it) {
            int R = (w * 4 + it) * 8 + lrow;
            gload16(&A[(size_t)(m0 + R) * DM + k0 + lch * 8], &At[(w * 4 + it) * 512]);
            if (it < 2) {
                int Rb = (w * 2 + it) * 8 + lrow;
                gload16(&B[(size_t)(n0 + Rb) * DM + k0 + lch * 8], &Bt[(w * 2 + it) * 512]);
            }
        }
        __syncthreads();
        fp16x8 af[4][2], bfr[2][2];
#pragma unroll
        for (int mf = 0; mf < 4; ++mf)
#pragma unroll
            for (int ks = 0; ks < 2; ++ks)
                af[mf][ks] = *(const fp16x8*)&At[(wr * 64 + mf * 16 + li) * 64 +
                                                 (((ks * 4 + lg) ^ (li & 7)) * 8)];
#pragma unroll
        for (int nf = 0; nf < 2; ++nf)
#pragma unroll
            for (int ks = 0; ks < 2; ++ks)
                bfr[nf][ks] = *(const fp16x8*)&Bt[(wc * 32 + nf * 16 + li) * 64 +
                                                  (((ks * 4 + lg) ^ (li & 7)) * 8)];
#pragma unroll
        for (int ks = 0; ks < 2; ++ks)
#pragma unroll
            for (int mf = 0; mf < 4; ++mf)
#pragma unroll
                for (int nf = 0; nf < 2; ++nf)
                    acc[mf][nf] = mfma16x16(af[mf][ks], bfr[nf][ks], acc[mf][nf]);
    }
#pragma unroll
    for (int nf = 0; nf < 2; ++nf) {
        int col = n0 + wc * 32 + nf * 16 + li;
        float bv_ = bias[col];
#pragma unroll
        for (int mf = 0; mf < 4; ++mf)
#pragma unroll
            for (int r2 = 0; r2 < 4; ++r2) {
                int row = m0 + wr * 64 + mf * 16 + lg * 4 + r2;
                outp[(size_t)row * DM + col] = acc[mf][nf][r2] + bv_;
            }
    }
}

// ---- Flash attention: swapped QK^T, 8 waves, no-max softmax, K/V LDS dbuf,
//      ONE barrier per KV tile (loads issued a full compute phase early).
__global__ __launch_bounds__(512) void attn_kernel(
    const fp16* __restrict__ Qb, const fp16* __restrict__ Kb,
    const fp16* __restrict__ Vtg, fp16* __restrict__ Of) {
    const int tid = threadIdx.x;
    const int lane = tid & 63;
    const int w = tid >> 6;                  // 0..7
    const int li = lane & 15, lg = lane >> 4;

    int L = blockIdx.x;
    L = (L & 7) * 64 + (L >> 3);             // bijective XCD swizzle (512 = 8*64)
    const int qt = L & 7, bh = L >> 3;
    const int b = bh >> 4, h = bh & 15;
    const size_t rowQ = (size_t)b * SEQ + (size_t)qt * 256;
    const int c0 = h * DK;

    __shared__ fp16 Kt[2][64 * 64];     // [kv][d], chunk-swizzled
    __shared__ fp16 Vt[2][64 * 64];     // [d][kv], chunk-swizzled
    __shared__ fp16 Pl[8][32 * 64];     // per-wave P [q][kv], chunk-swizzled

    fp16x8 qf[2][2];
#pragma unroll
    for (int mf = 0; mf < 2; ++mf)
#pragma unroll
        for (int ks = 0; ks < 2; ++ks)
            qf[mf][ks] = *(const fp16x8*)&Qb[(rowQ + w * 32 + mf * 16 + li) * DM +
                                             c0 + ks * 32 + lg * 8];

    fp16x8 ones;
#pragma unroll
    for (int j = 0; j < 8; ++j) ones[j] = (fp16)1.0f;

    f32x4 oacc[2][4] = {};
    f32x4 lacc[2] = {};

    const int sr = tid >> 3, sc = tid & 7;
    const int ssl = sc ^ (sr & 7);
    fp16x8 rk, rv;
    rk = *(const fp16x8*)&Kb[((size_t)b * SEQ + sr) * DM + c0 + sc * 8];
    rv = *(const fp16x8*)&Vtg[((size_t)bh * 64 + sr) * SEQ + sc * 8];
    *(fp16x8*)&Kt[0][sr * 64 + ssl * 8] = rk;
    *(fp16x8*)&Vt[0][sr * 64 + ssl * 8] = rv;
    __syncthreads();

    for (int kt = 0; kt < SEQ / 64; ++kt) {
        const int cur = kt & 1;
        const bool more = (kt + 1 < SEQ / 64);
        if (more) {                      // loads overlap the whole compute phase
            rk = *(const fp16x8*)&Kb[((size_t)b * SEQ + (kt + 1) * 64 + sr) * DM + c0 + sc * 8];
            rv = *(const fp16x8*)&Vtg[((size_t)bh * 64 + sr) * SEQ + (kt + 1) * 64 + sc * 8];
        }

        // S^T = K Q^T : lane holds q=li, kv=nf*16+lg*4+r
        f32x4 s[4][2] = {};
        __builtin_amdgcn_s_setprio(1);
#pragma unroll
        for (int nf = 0; nf < 4; ++nf)
#pragma unroll
            for (int ks = 0; ks < 2; ++ks) {
                fp16x8 kf = *(const fp16x8*)&Kt[cur][(nf * 16 + li) * 64 +
                                                     (((ks * 4 + lg) ^ (li & 7)) * 8)];
#pragma unroll
                for (int mf = 0; mf < 2; ++mf)
                    s[nf][mf] = mfma16x16(kf, qf[mf][ks], s[nf][mf]);
            }
        __builtin_amdgcn_s_setprio(0);

        // p = exp2(s) -> per-wave LDS (vectorized, swizzled)
#pragma unroll
        for (int mf = 0; mf < 2; ++mf) {
            fp16x4 pk[4];
#pragma unroll
            for (int nf = 0; nf < 4; ++nf)
#pragma unroll
                for (int r = 0; r < 4; ++r)
                    pk[nf][r] = (fp16)__builtin_amdgcn_exp2f(s[nf][mf][r]);
            int row = mf * 16 + li;
#pragma unroll
            for (int nf = 0; nf < 4; ++nf) {
                int sl = (nf * 2 + (lg >> 1)) ^ (li & 7);
                *(fp16x4*)&Pl[w][row * 64 + sl * 8 + (lg & 1) * 4] = pk[nf];
            }
        }

        // O += P V ; l += P 1
        __builtin_amdgcn_s_setprio(1);
#pragma unroll
        for (int ks = 0; ks < 2; ++ks) {
            fp16x8 pf[2];
#pragma unroll
            for (int mf = 0; mf < 2; ++mf) {
                pf[mf] = *(const fp16x8*)&Pl[w][(mf * 16 + li) * 64 +
                                                (((ks * 4 + lg) ^ (li & 7)) * 8)];
                lacc[mf] = mfma16x16(pf[mf], ones, lacc[mf]);
            }
#pragma unroll
            for (int nf = 0; nf < 4; ++nf) {
                fp16x8 vf = *(const fp16x8*)&Vt[cur][(nf * 16 + li) * 64 +
                                                     (((ks * 4 + lg) ^ (li & 7)) * 8)];
#pragma unroll
                for (int mf = 0; mf < 2; ++mf)
                    oacc[mf][nf] = mfma16x16(pf[mf], vf, oacc[mf][nf]);
            }
        }
        __builtin_amdgcn_s_setprio(0);

        if (more) {                      // stage tile kt+1 into the other buffer
            *(fp16x8*)&Kt[cur ^ 1][sr * 64 + ssl * 8] = rk;
            *(fp16x8*)&Vt[cur ^ 1][sr * 64 + ssl * 8] = rv;
            __syncthreads();             // one barrier per tile
        }
    }

    // epilogue: O /= l (lacc in oacc row layout), write fp16
#pragma unroll
    for (int mf = 0; mf < 2; ++mf) {
#pragma unroll
        for (int r = 0; r < 4; ++r) {
            float linv = 1.0f / lacc[mf][r];
            size_t row = rowQ + w * 32 + mf * 16 + lg * 4 + r;
#pragma unroll
            for (int nf = 0; nf < 4; ++nf) {
                int col = c0 + nf * 16 + li;
                Of[row * DM + col] = (fp16)(oacc[mf][nf][r] * linv);
            }
        }
    }
}

// ---------------------------------------------------------------------------
extern "C" void kernel_launch(void* const* d_in, const int* in_sizes, int n_in,
                              void* d_out, int out_size, void* d_ws, size_t ws_size,
                              hipStream_t stream) {
    const float* query = (const float*)d_in[0];
    const float* key   = (const float*)d_in[1];
    const float* value = (const float*)d_in[2];
    const float* wq    = (const float*)d_in[3];
    const float* bq    = (const float*)d_in[4];
    const float* wk    = (const float*)d_in[5];
    const float* bk    = (const float*)d_in[6];
    const float* wv    = (const float*)d_in[7];
    const float* bv    = (const float*)d_in[8];
    const float* wo    = (const float*)d_in[9];
    const float* bo    = (const float*)d_in[10];

    char* ws = (char*)d_ws;
    const size_t SZX = (size_t)NROWS * DM * 2;   // 16 MB (fp16)
    const size_t SZW = (size_t)DM * DM * 2;      //  2 MB (fp16)
    fp16* Wtq = (fp16*)(ws);
    fp16* Wtk = (fp16*)(ws + SZW);
    fp16* Wtv = (fp16*)(ws + 2 * SZW);
    fp16* Wto = (fp16*)(ws + 3 * SZW);
    fp16* Qb  = (fp16*)(ws + 4 * SZW);
    fp16* Kb  = (fp16*)(ws + 4 * SZW + SZX);
    fp16* Vtg = (fp16*)(ws + 4 * SZW + 2 * SZX); // V^T [b*1024+h*64+d][s]
    fp16* Of  = (fp16*)(ws + 4 * SZW + 3 * SZX); // 72 MB total

    const dim3 bT(32, 8);

    transpose_w_kernel<<<dim3(32, 32, 4), bT, 0, stream>>>(
        wq, wk, wv, wo, Wtq, Wtk, Wtv, Wto);
    gemm_qkv_kernel<<<1536, 256, 0, stream>>>(
        query, key, value, Wtq, Wtk, Wtv, bq, bk, bv, Qb, Kb, Vtg);
    attn_kernel<<<512, 512, 0, stream>>>(Qb, Kb, Vtg, Of);
    gemm_out_kernel<<<1024, 256, 0, stream>>>(Of, Wto, bo, (float*)d_out);
}

// Round 10
// 212.170 us; speedup vs baseline: 1.5015x; 1.5015x over previous
//
#include <hip/hip_runtime.h>

// ---------------------------------------------------------------------------
// MultiHeadAttention: B=4, S=2048, D=1024, H=16, dk=64
// R10: QKV GEMM reverted to the measured-best R6 structure (fp16 A via
//      separate cast kernels, dual global_load_lds staging, 2 barriers/step,
//      high TLP) combined with R8's proven XCD-aware decode (FETCH 200->74MB).
//      R9's latency-serialized single-barrier pipeline abandoned.
//      Attention / out-projection / transposes unchanged (known-good).
// ---------------------------------------------------------------------------

typedef _Float16 fp16;
typedef fp16  fp16x8 __attribute__((ext_vector_type(8)));
typedef fp16  fp16x4 __attribute__((ext_vector_type(4)));
typedef float f32x4  __attribute__((ext_vector_type(4)));

#define NROWS 8192     // B*S
#define DM    1024
#define SEQ   2048
#define DK    64
#define LOG2E 1.44269504088896340736f
#define QSCALE (0.125f * LOG2E)

__device__ __forceinline__ f32x4 mfma16x16(fp16x8 a, fp16x8 b, f32x4 c) {
    return __builtin_amdgcn_mfma_f32_16x16x32_f16(a, b, c, 0, 0, 0);
}

__device__ __forceinline__ void gload16(const void* g, void* l) {
    __builtin_amdgcn_global_load_lds(
        (const __attribute__((address_space(1))) void*)g,
        (__attribute__((address_space(3))) void*)l, 16, 0, 0);
}

// ---- fp32 -> fp16 cast, z-batched over 3 tensors -------------------------
__global__ __launch_bounds__(256) void cast_fp16_kernel(
    const float* __restrict__ x0, const float* __restrict__ x1,
    const float* __restrict__ x2,
    fp16* __restrict__ y0, fp16* __restrict__ y1, fp16* __restrict__ y2,
    int n4) {
    const int z = blockIdx.y;
    const float* x = (z == 0) ? x0 : (z == 1) ? x1 : x2;
    fp16*       y = (z == 0) ? y0 : (z == 1) ? y1 : y2;
    int i = blockIdx.x * 256 + threadIdx.x;
    if (i >= n4) return;
    const float4 v = ((const float4*)x)[i];
    fp16x4 o;
    o[0] = (fp16)v.x; o[1] = (fp16)v.y; o[2] = (fp16)v.z; o[3] = (fp16)v.w;
    ((fp16x4*)y)[i] = o;
}

// ---- transpose 1024x1024 fp32 W[k][n] -> fp16 T[n][k], z-batched x4 ------
__global__ __launch_bounds__(256) void transpose_w_kernel(
    const float* __restrict__ w0, const float* __restrict__ w1,
    const float* __restrict__ w2, const float* __restrict__ w3,
    fp16* __restrict__ t0, fp16* __restrict__ t1,
    fp16* __restrict__ t2, fp16* __restrict__ t3) {
    const int z = blockIdx.z;
    const float* W = (z == 0) ? w0 : (z == 1) ? w1 : (z == 2) ? w2 : w3;
    fp16*       T = (z == 0) ? t0 : (z == 1) ? t1 : (z == 2) ? t2 : t3;
    __shared__ float tile[32][33];
    const int tx = threadIdx.x, ty = threadIdx.y;
    const int bx = blockIdx.x * 32, by = blockIdx.y * 32;
#pragma unroll
    for (int j = 0; j < 4; ++j)
        tile[ty + 8 * j][tx] = W[(size_t)(by + ty + 8 * j) * DM + bx + tx];
    __syncthreads();
#pragma unroll
    for (int j = 0; j < 4; ++j)
        T[(size_t)(bx + ty + 8 * j) * DM + by + tx] = (fp16)tile[tx][ty + 8 * j];
}

// ---- QKV projection GEMM: fp16 A and B via dual global_load_lds ----------
// Grid: 1536 1D. Decode: XCD x = i&7 owns m-slabs [x*8, x*8+8) for all n,z
// (A-panels L2-resident per XCD). 2 barriers per K-step, ~5 blocks/CU TLP.
// z 0: Q (scale, row-major out), 1: K, 2: V (V^T layout out).
__global__ __launch_bounds__(256) void gemm_qkv_kernel(
    const fp16* __restrict__ Xq, const fp16* __restrict__ Xk,
    const fp16* __restrict__ Xv,
    const fp16* __restrict__ Wq, const fp16* __restrict__ Wk,
    const fp16* __restrict__ Wv,
    const float* __restrict__ bq, const float* __restrict__ bk,
    const float* __restrict__ bv,
    fp16* __restrict__ Qb, fp16* __restrict__ Kb, fp16* __restrict__ Vtg) {
    const int i = blockIdx.x;
    const int xcd = i & 7, r = i >> 3;           // r in [0,192)
    const int z = r >> 6, rr = r & 63;
    const int m0 = (xcd * 8 + (rr >> 3)) * 128;  // m-slab, XCD-local
    const int n0 = (rr & 7) * 128;

    const fp16* __restrict__ A = (z == 0) ? Xq : (z == 1) ? Xk : Xv;
    const fp16* __restrict__ B = (z == 0) ? Wq : (z == 1) ? Wk : Wv;
    const float* __restrict__ bias = (z == 0) ? bq : (z == 1) ? bk : bv;
    fp16* __restrict__ outp = (z == 0) ? Qb : (z == 1) ? Kb : Vtg;
    const float oscale = (z == 0) ? QSCALE : 1.0f;

    const int tid = threadIdx.x;
    const int lane = tid & 63;
    const int w = tid >> 6;
    const int wr = w >> 1, wc = w & 1;
    const int li = lane & 15, lg = lane >> 4;
    const int lrow = lane >> 3;
    const int lch  = (lane & 7) ^ lrow;          // pre-swizzled source chunk

    __shared__ fp16 At[128 * 64];
    __shared__ fp16 Bt[128 * 64];

    f32x4 acc[4][4] = {};

    for (int k0 = 0; k0 < DM; k0 += 64) {
        __syncthreads();
#pragma unroll
        for (int it = 0; it < 4; ++it) {
            int R = (w * 4 + it) * 8 + lrow;
            gload16(&A[(size_t)(m0 + R) * DM + k0 + lch * 8], &At[(w * 4 + it) * 512]);
            gload16(&B[(size_t)(n0 + R) * DM + k0 + lch * 8], &Bt[(w * 4 + it) * 512]);
        }
        __syncthreads();
        fp16x8 af[4][2], bfr[4][2];
#pragma unroll
        for (int mf = 0; mf < 4; ++mf)
#pragma unroll
            for (int ks = 0; ks < 2; ++ks)
                af[mf][ks] = *(const fp16x8*)&At[(wr * 64 + mf * 16 + li) * 64 +
                                                 (((ks * 4 + lg) ^ (li & 7)) * 8)];
#pragma unroll
        for (int nf = 0; nf < 4; ++nf)
#pragma unroll
            for (int ks = 0; ks < 2; ++ks)
                bfr[nf][ks] = *(const fp16x8*)&Bt[(wc * 64 + nf * 16 + li) * 64 +
                                                  (((ks * 4 + lg) ^ (li & 7)) * 8)];
#pragma unroll
        for (int ks = 0; ks < 2; ++ks)
#pragma unroll
            for (int mf = 0; mf < 4; ++mf)
#pragma unroll
                for (int nf = 0; nf < 4; ++nf)
                    acc[mf][nf] = mfma16x16(af[mf][ks], bfr[nf][ks], acc[mf][nf]);
    }
#pragma unroll
    for (int nf = 0; nf < 4; ++nf) {
        int col = n0 + wc * 64 + nf * 16 + li;
        float bv_ = bias[col];
        if (z == 2) {           // V^T layout [b*1024 + col][s]
#pragma unroll
            for (int mf = 0; mf < 4; ++mf) {
                int rowb = m0 + wr * 64 + mf * 16 + lg * 4;
                fp16x4 pk;
#pragma unroll
                for (int r2 = 0; r2 < 4; ++r2)
                    pk[r2] = (fp16)(acc[mf][nf][r2] + bv_);
                size_t o = ((size_t)(rowb >> 11) * 1024 + col) * SEQ + (rowb & 2047);
                *(fp16x4*)&outp[o] = pk;
            }
        } else {
#pragma unroll
            for (int mf = 0; mf < 4; ++mf)
#pragma unroll
                for (int r2 = 0; r2 < 4; ++r2) {
                    int row = m0 + wr * 64 + mf * 16 + lg * 4 + r2;
                    outp[(size_t)row * DM + col] = (fp16)((acc[mf][nf][r2] + bv_) * oscale);
                }
        }
    }
}

// ---- Out-projection GEMM: fp16 A/B, 128x64 tile, XCD-aware decode --------
__global__ __launch_bounds__(256) void gemm_out_kernel(
    const fp16* __restrict__ A, const fp16* __restrict__ B,
    const float* __restrict__ bias, float* __restrict__ outp) {
    const int i = blockIdx.x;
    const int xcd = i & 7, r = i >> 3;           // r in [0,128)
    const int m0 = (xcd * 8 + (r >> 4)) * 128;
    const int n0 = (r & 15) * 64;

    const int tid = threadIdx.x;
    const int lane = tid & 63;
    const int w = tid >> 6;
    const int wr = w >> 1, wc = w & 1;
    const int li = lane & 15, lg = lane >> 4;
    const int lrow = lane >> 3;
    const int lch  = (lane & 7) ^ lrow;

    __shared__ fp16 At[128 * 64];
    __shared__ fp16 Bt[64 * 64];

    f32x4 acc[4][2] = {};

    for (int k0 = 0; k0 < DM; k0 += 64) {
        __syncthreads();
#pragma unroll
        for (int it = 0; it < 4; ++it) {
            int R = (w * 4 + it) * 8 + lrow;
            gload16(&A[(size_t)(m0 + R) * DM + k0 + lch * 8], &At[(w * 4 + it) * 512]);
            if (it < 2) {
                int Rb = (w * 2 + it) * 8 + lrow;
                gload16(&B[(size_t)(n0 + Rb) * DM + k0 + lch * 8], &Bt[(w * 2 + it) * 512]);
            }
        }
        __syncthreads();
        fp16x8 af[4][2], bfr[2][2];
#pragma unroll
        for (int mf = 0; mf < 4; ++mf)
#pragma unroll
            for (int ks = 0; ks < 2; ++ks)
                af[mf][ks] = *(const fp16x8*)&At[(wr * 64 + mf * 16 + li) * 64 +
                                                 (((ks * 4 + lg) ^ (li & 7)) * 8)];
#pragma unroll
        for (int nf = 0; nf < 2; ++nf)
#pragma unroll
            for (int ks = 0; ks < 2; ++ks)
                bfr[nf][ks] = *(const fp16x8*)&Bt[(wc * 32 + nf * 16 + li) * 64 +
                                                  (((ks * 4 + lg) ^ (li & 7)) * 8)];
#pragma unroll
        for (int ks = 0; ks < 2; ++ks)
#pragma unroll
            for (int mf = 0; mf < 4; ++mf)
#pragma unroll
                for (int nf = 0; nf < 2; ++nf)
                    acc[mf][nf] = mfma16x16(af[mf][ks], bfr[nf][ks], acc[mf][nf]);
    }
#pragma unroll
    for (int nf = 0; nf < 2; ++nf) {
        int col = n0 + wc * 32 + nf * 16 + li;
        float bv_ = bias[col];
#pragma unroll
        for (int mf = 0; mf < 4; ++mf)
#pragma unroll
            for (int r2 = 0; r2 < 4; ++r2) {
                int row = m0 + wr * 64 + mf * 16 + lg * 4 + r2;
                outp[(size_t)row * DM + col] = acc[mf][nf][r2] + bv_;
            }
    }
}

// ---- Flash attention: swapped QK^T, 8 waves, no-max softmax, K/V LDS dbuf,
//      ONE barrier per KV tile (loads issued a full compute phase early).
__global__ __launch_bounds__(512) void attn_kernel(
    const fp16* __restrict__ Qb, const fp16* __restrict__ Kb,
    const fp16* __restrict__ Vtg, fp16* __restrict__ Of) {
    const int tid = threadIdx.x;
    const int lane = tid & 63;
    const int w = tid >> 6;                  // 0..7
    const int li = lane & 15, lg = lane >> 4;

    int L = blockIdx.x;
    L = (L & 7) * 64 + (L >> 3);             // bijective XCD swizzle (512 = 8*64)
    const int qt = L & 7, bh = L >> 3;
    const int b = bh >> 4, h = bh & 15;
    const size_t rowQ = (size_t)b * SEQ + (size_t)qt * 256;
    const int c0 = h * DK;

    __shared__ fp16 Kt[2][64 * 64];     // [kv][d], chunk-swizzled
    __shared__ fp16 Vt[2][64 * 64];     // [d][kv], chunk-swizzled
    __shared__ fp16 Pl[8][32 * 64];     // per-wave P [q][kv], chunk-swizzled

    fp16x8 qf[2][2];
#pragma unroll
    for (int mf = 0; mf < 2; ++mf)
#pragma unroll
        for (int ks = 0; ks < 2; ++ks)
            qf[mf][ks] = *(const fp16x8*)&Qb[(rowQ + w * 32 + mf * 16 + li) * DM +
                                             c0 + ks * 32 + lg * 8];

    fp16x8 ones;
#pragma unroll
    for (int j = 0; j < 8; ++j) ones[j] = (fp16)1.0f;

    f32x4 oacc[2][4] = {};
    f32x4 lacc[2] = {};

    const int sr = tid >> 3, sc = tid & 7;
    const int ssl = sc ^ (sr & 7);
    fp16x8 rk, rv;
    rk = *(const fp16x8*)&Kb[((size_t)b * SEQ + sr) * DM + c0 + sc * 8];
    rv = *(const fp16x8*)&Vtg[((size_t)bh * 64 + sr) * SEQ + sc * 8];
    *(fp16x8*)&Kt[0][sr * 64 + ssl * 8] = rk;
    *(fp16x8*)&Vt[0][sr * 64 + ssl * 8] = rv;
    __syncthreads();

    for (int kt = 0; kt < SEQ / 64; ++kt) {
        const int cur = kt & 1;
        const bool more = (kt + 1 < SEQ / 64);
        if (more) {                      // loads overlap the whole compute phase
            rk = *(const fp16x8*)&Kb[((size_t)b * SEQ + (kt + 1) * 64 + sr) * DM + c0 + sc * 8];
            rv = *(const fp16x8*)&Vtg[((size_t)bh * 64 + sr) * SEQ + (kt + 1) * 64 + sc * 8];
        }

        // S^T = K Q^T : lane holds q=li, kv=nf*16+lg*4+r
        f32x4 s[4][2] = {};
        __builtin_amdgcn_s_setprio(1);
#pragma unroll
        for (int nf = 0; nf < 4; ++nf)
#pragma unroll
            for (int ks = 0; ks < 2; ++ks) {
                fp16x8 kf = *(const fp16x8*)&Kt[cur][(nf * 16 + li) * 64 +
                                                     (((ks * 4 + lg) ^ (li & 7)) * 8)];
#pragma unroll
                for (int mf = 0; mf < 2; ++mf)
                    s[nf][mf] = mfma16x16(kf, qf[mf][ks], s[nf][mf]);
            }
        __builtin_amdgcn_s_setprio(0);

        // p = exp2(s) -> per-wave LDS (vectorized, swizzled)
#pragma unroll
        for (int mf = 0; mf < 2; ++mf) {
            fp16x4 pk[4];
#pragma unroll
            for (int nf = 0; nf < 4; ++nf)
#pragma unroll
                for (int r = 0; r < 4; ++r)
                    pk[nf][r] = (fp16)__builtin_amdgcn_exp2f(s[nf][mf][r]);
            int row = mf * 16 + li;
#pragma unroll
            for (int nf = 0; nf < 4; ++nf) {
                int sl = (nf * 2 + (lg >> 1)) ^ (li & 7);
                *(fp16x4*)&Pl[w][row * 64 + sl * 8 + (lg & 1) * 4] = pk[nf];
            }
        }

        // O += P V ; l += P 1
        __builtin_amdgcn_s_setprio(1);
#pragma unroll
        for (int ks = 0; ks < 2; ++ks) {
            fp16x8 pf[2];
#pragma unroll
            for (int mf = 0; mf < 2; ++mf) {
                pf[mf] = *(const fp16x8*)&Pl[w][(mf * 16 + li) * 64 +
                                                (((ks * 4 + lg) ^ (li & 7)) * 8)];
                lacc[mf] = mfma16x16(pf[mf], ones, lacc[mf]);
            }
#pragma unroll
            for (int nf = 0; nf < 4; ++nf) {
                fp16x8 vf = *(const fp16x8*)&Vt[cur][(nf * 16 + li) * 64 +
                                                     (((ks * 4 + lg) ^ (li & 7)) * 8)];
#pragma unroll
                for (int mf = 0; mf < 2; ++mf)
                    oacc[mf][nf] = mfma16x16(pf[mf], vf, oacc[mf][nf]);
            }
        }
        __builtin_amdgcn_s_setprio(0);

        if (more) {                      // stage tile kt+1 into the other buffer
            *(fp16x8*)&Kt[cur ^ 1][sr * 64 + ssl * 8] = rk;
            *(fp16x8*)&Vt[cur ^ 1][sr * 64 + ssl * 8] = rv;
            __syncthreads();             // one barrier per tile
        }
    }

    // epilogue: O /= l (lacc in oacc row layout), write fp16
#pragma unroll
    for (int mf = 0; mf < 2; ++mf) {
#pragma unroll
        for (int r = 0; r < 4; ++r) {
            float linv = 1.0f / lacc[mf][r];
            size_t row = rowQ + w * 32 + mf * 16 + lg * 4 + r;
#pragma unroll
            for (int nf = 0; nf < 4; ++nf) {
                int col = c0 + nf * 16 + li;
                Of[row * DM + col] = (fp16)(oacc[mf][nf][r] * linv);
            }
        }
    }
}

// ---------------------------------------------------------------------------
extern "C" void kernel_launch(void* const* d_in, const int* in_sizes, int n_in,
                              void* d_out, int out_size, void* d_ws, size_t ws_size,
                              hipStream_t stream) {
    const float* query = (const float*)d_in[0];
    const float* key   = (const float*)d_in[1];
    const float* value = (const float*)d_in[2];
    const float* wq    = (const float*)d_in[3];
    const float* bq    = (const float*)d_in[4];
    const float* wk    = (const float*)d_in[5];
    const float* bk    = (const float*)d_in[6];
    const float* wv    = (const float*)d_in[7];
    const float* bv    = (const float*)d_in[8];
    const float* wo    = (const float*)d_in[9];
    const float* bo    = (const float*)d_in[10];

    char* ws = (char*)d_ws;
    const size_t SZX = (size_t)NROWS * DM * 2;   // 16 MB (fp16)
    const size_t SZW = (size_t)DM * DM * 2;      //  2 MB (fp16)
    fp16* Xq  = (fp16*)(ws);
    fp16* Xk  = (fp16*)(ws + SZX);
    fp16* Xv  = (fp16*)(ws + 2 * SZX);
    fp16* Wtq = (fp16*)(ws + 3 * SZX);
    fp16* Wtk = (fp16*)(ws + 3 * SZX + SZW);
    fp16* Wtv = (fp16*)(ws + 3 * SZX + 2 * SZW);
    fp16* Wto = (fp16*)(ws + 3 * SZX + 3 * SZW);
    fp16* Qb  = (fp16*)(ws + 3 * SZX + 4 * SZW);
    fp16* Kb  = (fp16*)(ws + 4 * SZX + 4 * SZW);
    fp16* Vtg = (fp16*)(ws + 5 * SZX + 4 * SZW); // V^T [b*1024+h*64+d][s]
    fp16* Of  = Xq;                              // Xq dead after QKV GEMMs

    const int n4 = NROWS * DM / 4;
    const dim3 bT(32, 8);

    cast_fp16_kernel<<<dim3(8192, 3), 256, 0, stream>>>(
        query, key, value, Xq, Xk, Xv, n4);
    transpose_w_kernel<<<dim3(32, 32, 4), bT, 0, stream>>>(
        wq, wk, wv, wo, Wtq, Wtk, Wtv, Wto);
    gemm_qkv_kernel<<<1536, 256, 0, stream>>>(
        Xq, Xk, Xv, Wtq, Wtk, Wtv, bq, bk, bv, Qb, Kb, Vtg);
    attn_kernel<<<512, 512, 0, stream>>>(Qb, Kb, Vtg, Of);
    gemm_out_kernel<<<1024, 256, 0, stream>>>(Of, Wto, bo, (float*)d_out);
}